// Round 1
// baseline (138.689 us; speedup 1.0000x reference)
//
#include <hip/hip_runtime.h>
#include <math.h>

// ---------------------------------------------------------------------------
// Quantum layer: 4 qubits, 16 amplitudes.
// The circuit after angle-embedding is batch-independent: compose it once into
// a 16x16 complex unitary U (setup kernel), then per sample do
//   s[16] = product state from RY(x) embedding  (real)
//   a = U * s                                    (complex * real matvec)
//   <Z_w> = sum_b (+/-)|a[b]|^2
// ---------------------------------------------------------------------------

// Setup: thread j evolves basis state e_j through 4 layers of Rot + CNOT ring.
// Output layout in ws: Ur[j][b] = Re U[b][j] at ws[j*16+b], Ui at ws[256+j*16+b]
__global__ void build_unitary(const float* __restrict__ qw, float* __restrict__ U) {
    int j = threadIdx.x;
    if (j >= 16) return;
    float ar[16], ai[16];
#pragma unroll
    for (int b = 0; b < 16; ++b) { ar[b] = (b == j) ? 1.f : 0.f; ai[b] = 0.f; }

    for (int l = 0; l < 4; ++l) {
        // per-qubit Rot gates
        for (int w = 0; w < 4; ++w) {
            float phi   = qw[(l * 4 + w) * 3 + 0];
            float theta = qw[(l * 4 + w) * 3 + 1];
            float omega = qw[(l * 4 + w) * 3 + 2];
            float ct = cosf(0.5f * theta), st = sinf(0.5f * theta);
            float ha = 0.5f * (phi + omega), hd = 0.5f * (phi - omega);
            float emr = cosf(ha), emi = -sinf(ha);   // e^{-i(phi+omega)/2}
            float edr = cosf(hd), edi =  sinf(hd);   // e^{+i(phi-omega)/2}
            // Rot = [[em*ct, -ed*st], [conj(ed)*st, conj(em)*ct]]
            float u00r =  emr * ct, u00i =  emi * ct;
            float u01r = -edr * st, u01i = -edi * st;
            float u10r =  edr * st, u10i = -edi * st;
            float u11r =  emr * ct, u11i = -emi * ct;
            int mask = 8 >> w;   // wire w <-> bit (3-w)
            for (int b = 0; b < 16; ++b) {
                if (b & mask) continue;
                int b1 = b | mask;
                float xr = ar[b], xi = ai[b], yr = ar[b1], yi = ai[b1];
                ar[b]  = u00r * xr - u00i * xi + u01r * yr - u01i * yi;
                ai[b]  = u00r * xi + u00i * xr + u01r * yi + u01i * yr;
                ar[b1] = u10r * xr - u10i * xi + u11r * yr - u11i * yi;
                ai[b1] = u10r * xi + u10i * xr + u11r * yi + u11i * yr;
            }
        }
        // CNOT ring: (0,1),(1,2),(2,3),(3,0); swap target amps where control=1
        for (int w = 0; w < 4; ++w) {
            int cm = 8 >> w, tm = 8 >> ((w + 1) & 3);
            for (int b = 0; b < 16; ++b) {
                if ((b & cm) && !(b & tm)) {
                    int b1 = b | tm;
                    float tr = ar[b], ti = ai[b];
                    ar[b] = ar[b1]; ai[b] = ai[b1];
                    ar[b1] = tr;    ai[b1] = ti;
                }
            }
        }
    }
#pragma unroll
    for (int b = 0; b < 16; ++b) {
        U[j * 16 + b]       = ar[b];
        U[256 + j * 16 + b] = ai[b];
    }
}

__global__ __launch_bounds__(256) void qlayer_main(
        const float4* __restrict__ x, const float* __restrict__ U,
        float4* __restrict__ out, int B) {
    int stride = gridDim.x * blockDim.x;
    for (int i = blockIdx.x * blockDim.x + threadIdx.x; i < B; i += stride) {
        float4 xv = x[i];
        float c0, s0, c1, s1, c2, s2, c3, s3;
        __sincosf(0.5f * xv.x, &s0, &c0);
        __sincosf(0.5f * xv.y, &s1, &c1);
        __sincosf(0.5f * xv.z, &s2, &c2);
        __sincosf(0.5f * xv.w, &s3, &c3);
        // s[b0b1b2b3] = f0(b0) f1(b1) f2(b2) f3(b3), b0 = MSB
        float p01[4] = {c0 * c1, c0 * s1, s0 * c1, s0 * s1};
        float p23[4] = {c2 * c3, c2 * s3, s2 * c3, s2 * s3};
        float sv[16];
#pragma unroll
        for (int a = 0; a < 4; ++a)
#pragma unroll
            for (int b = 0; b < 4; ++b) sv[a * 4 + b] = p01[a] * p23[b];

        float are[16], aim[16];
#pragma unroll
        for (int b = 0; b < 16; ++b) { are[b] = 0.f; aim[b] = 0.f; }
#pragma unroll
        for (int j = 0; j < 16; ++j) {
            float sj = sv[j];
#pragma unroll
            for (int b = 0; b < 16; ++b) {
                are[b] = fmaf(U[j * 16 + b],       sj, are[b]);
                aim[b] = fmaf(U[256 + j * 16 + b], sj, aim[b]);
            }
        }
        float e0 = 0.f, e1 = 0.f, e2 = 0.f, e3 = 0.f;
#pragma unroll
        for (int b = 0; b < 16; ++b) {
            float p = fmaf(are[b], are[b], aim[b] * aim[b]);
            e0 = (b & 8) ? e0 - p : e0 + p;
            e1 = (b & 4) ? e1 - p : e1 + p;
            e2 = (b & 2) ? e2 - p : e2 + p;
            e3 = (b & 1) ? e3 - p : e3 + p;
        }
        out[i] = make_float4(e0, e1, e2, e3);
    }
}

extern "C" void kernel_launch(void* const* d_in, const int* in_sizes, int n_in,
                              void* d_out, int out_size, void* d_ws, size_t ws_size,
                              hipStream_t stream) {
    const float4* x  = (const float4*)d_in[0];   // (B,4) float32
    const float*  qw = (const float*)d_in[1];    // (4,4,3) float32
    float* U = (float*)d_ws;                     // 512 floats: Ur then Ui
    float4* out = (float4*)d_out;                // (B,4) float32
    int B = in_sizes[0] / 4;

    hipLaunchKernelGGL(build_unitary, dim3(1), dim3(64), 0, stream, qw, U);

    const int threads = 256;
    const int spt = 4;  // samples per thread
    int blocks = (B + threads * spt - 1) / (threads * spt);
    if (blocks < 1) blocks = 1;
    hipLaunchKernelGGL(qlayer_main, dim3(blocks), dim3(threads), 0, stream,
                       x, U, out, B);
}

// Round 2
// 92.753 us; speedup vs baseline: 1.4952x; 1.4952x over previous
//
#include <hip/hip_runtime.h>
#include <math.h>

// ---------------------------------------------------------------------------
// 4-qubit statevector layer. The post-embedding circuit is batch-independent:
// compose it into a 16x16 complex unitary U once (build_unitary), then per
// sample: product state s (real, rank-1), a = U*s, <Z_w> = WHT signs of |a|^2.
// U layout: row j = [Re U[0..15][j] | Im U[0..15][j]], 32 floats, contiguous.
// ---------------------------------------------------------------------------

__global__ void build_unitary(const float* __restrict__ qw, float* __restrict__ U) {
    // Stage 1: threads 0..15 compute gate matrices (parallel trig) into LDS.
    __shared__ float g[16][8];  // u00r,u00i,u01r,u01i,u10r,u10i,u11r,u11i
    int t = threadIdx.x;
    if (t < 16) {
        float phi = qw[t * 3 + 0], theta = qw[t * 3 + 1], omega = qw[t * 3 + 2];
        float ct = cosf(0.5f * theta), st = sinf(0.5f * theta);
        float ha = 0.5f * (phi + omega), hd = 0.5f * (phi - omega);
        float emr = cosf(ha), emi = -sinf(ha);   // e^{-i(phi+omega)/2}
        float edr = cosf(hd), edi =  sinf(hd);   // e^{+i(phi-omega)/2}
        g[t][0] =  emr * ct; g[t][1] =  emi * ct;   // u00
        g[t][2] = -edr * st; g[t][3] = -edi * st;   // u01
        g[t][4] =  edr * st; g[t][5] = -edi * st;   // u10
        g[t][6] =  emr * ct; g[t][7] = -emi * ct;   // u11
    }
    __syncthreads();
    if (t >= 16) return;
    // Stage 2: thread t evolves basis column e_t through the circuit.
    float ar[16], ai[16];
#pragma unroll
    for (int b = 0; b < 16; ++b) { ar[b] = (b == t) ? 1.f : 0.f; ai[b] = 0.f; }
#pragma unroll
    for (int l = 0; l < 4; ++l) {
#pragma unroll
        for (int w = 0; w < 4; ++w) {
            int gi = l * 4 + w;
            float u00r = g[gi][0], u00i = g[gi][1], u01r = g[gi][2], u01i = g[gi][3];
            float u10r = g[gi][4], u10i = g[gi][5], u11r = g[gi][6], u11i = g[gi][7];
            int mask = 8 >> w;   // wire w <-> bit (3-w)
#pragma unroll
            for (int b = 0; b < 16; ++b) {
                if (b & mask) continue;
                int b1 = b | mask;
                float xr = ar[b], xi = ai[b], yr = ar[b1], yi = ai[b1];
                ar[b]  = u00r * xr - u00i * xi + u01r * yr - u01i * yi;
                ai[b]  = u00r * xi + u00i * xr + u01r * yi + u01i * yr;
                ar[b1] = u10r * xr - u10i * xi + u11r * yr - u11i * yi;
                ai[b1] = u10r * xi + u10i * xr + u11r * yi + u11i * yr;
            }
        }
#pragma unroll
        for (int w = 0; w < 4; ++w) {   // CNOT ring
            int cm = 8 >> w, tm = 8 >> ((w + 1) & 3);
#pragma unroll
            for (int b = 0; b < 16; ++b) {
                if ((b & cm) && !(b & tm)) {
                    int b1 = b | tm;
                    float tr = ar[b], ti = ai[b];
                    ar[b] = ar[b1]; ai[b] = ai[b1];
                    ar[b1] = tr;    ai[b1] = ti;
                }
            }
        }
    }
#pragma unroll
    for (int b = 0; b < 16; ++b) {
        U[t * 32 + b]      = ar[b];   // Re U[b][t]
        U[t * 32 + 16 + b] = ai[b];   // Im U[b][t]
    }
}

__global__ __launch_bounds__(256) void qlayer_main(
        const float4* __restrict__ x, const float* __restrict__ U,
        float4* __restrict__ out, int B) {
    __shared__ float svs[256 * 17];   // per-thread 16 floats, stride 17 (bank-spread)
    int tid = threadIdx.x;
    int i = blockIdx.x * 256 + tid;
    if (i >= B) return;

    float4 xv = x[i];
    float c0, s0, c1, s1, c2, s2, c3, s3;
    __sincosf(0.5f * xv.x, &s0, &c0);
    __sincosf(0.5f * xv.y, &s1, &c1);
    __sincosf(0.5f * xv.z, &s2, &c2);
    __sincosf(0.5f * xv.w, &s3, &c3);
    float p01[4] = {c0 * c1, c0 * s1, s0 * c1, s0 * s1};
    float p23[4] = {c2 * c3, c2 * s3, s2 * c3, s2 * s3};
    float* mysv = &svs[tid * 17];
#pragma unroll
    for (int a = 0; a < 4; ++a)
#pragma unroll
        for (int b = 0; b < 4; ++b) mysv[a * 4 + b] = p01[a] * p23[b];

    // 32 accumulators forced live across a real loop back-edge -> 32
    // independent FMA chains per iteration (breadth-first, latency-hidden).
    float are[16], aim[16];
#pragma unroll
    for (int b = 0; b < 16; ++b) { are[b] = 0.f; aim[b] = 0.f; }
#pragma unroll 2
    for (int j = 0; j < 16; ++j) {
        float sj = mysv[j];
        const float* row = U + j * 32;  // uniform -> s_load_dwordx16 x2
#pragma unroll
        for (int b = 0; b < 16; ++b) {
            are[b] = fmaf(row[b],      sj, are[b]);
            aim[b] = fmaf(row[16 + b], sj, aim[b]);
        }
    }

    float p[16];
#pragma unroll
    for (int b = 0; b < 16; ++b) p[b] = fmaf(are[b], are[b], aim[b] * aim[b]);

    // Walsh-Hadamard style signed reductions: e_w = sum_b (-1)^{bit_w} p[b]
    float s8[8], d8[8];
#pragma unroll
    for (int k = 0; k < 8; ++k) { s8[k] = p[2*k] + p[2*k+1]; d8[k] = p[2*k] - p[2*k+1]; }
    float e3 = ((d8[0]+d8[1])+(d8[2]+d8[3]))+((d8[4]+d8[5])+(d8[6]+d8[7]));
    float u4[4], v4[4];
#pragma unroll
    for (int m = 0; m < 4; ++m) { u4[m] = s8[2*m] + s8[2*m+1]; v4[m] = s8[2*m] - s8[2*m+1]; }
    float e2 = (v4[0]+v4[1])+(v4[2]+v4[3]);
    float x0 = u4[0]+u4[1], x1 = u4[2]+u4[3];
    float y0 = u4[0]-u4[1], y1 = u4[2]-u4[3];
    float e1 = y0 + y1;
    float e0 = x0 - x1;

    out[i] = make_float4(e0, e1, e2, e3);
}

extern "C" void kernel_launch(void* const* d_in, const int* in_sizes, int n_in,
                              void* d_out, int out_size, void* d_ws, size_t ws_size,
                              hipStream_t stream) {
    const float4* x  = (const float4*)d_in[0];   // (B,4) float32
    const float*  qw = (const float*)d_in[1];    // (4,4,3) float32
    float* U = (float*)d_ws;                     // 512 floats, row-j layout
    float4* out = (float4*)d_out;                // (B,4) float32
    int B = in_sizes[0] / 4;

    hipLaunchKernelGGL(build_unitary, dim3(1), dim3(64), 0, stream, qw, U);

    int blocks = (B + 255) / 256;
    hipLaunchKernelGGL(qlayer_main, dim3(blocks), dim3(256), 0, stream,
                       x, U, out, B);
}

// Round 3
// 84.549 us; speedup vs baseline: 1.6403x; 1.0970x over previous
//
#include <hip/hip_runtime.h>
#include <math.h>

// ---------------------------------------------------------------------------
// 4-qubit statevector layer, fully collapsed:
// Embedded state is REAL (RY embedding), so <Y>=0 per qubit and
//   e_w = sum_{t in {I,X,Z}^4} C_w[t] * prod_k m_k[t_k],  m_k = [1, sin x, cos x]
// with C_w[t] = (1/16) tr(Re(U^dag Z_w U) P_t), U = fixed 16x16 circuit unitary.
// build_C computes C (4 x 81 floats) once; main kernel is a 360-FMA bilinear
// contraction per sample with C broadcast from LDS.
// ---------------------------------------------------------------------------

__global__ void build_C(const float* __restrict__ qw, float* __restrict__ Cg) {
    __shared__ float g[16][8];        // per-gate 2x2 complex entries
    __shared__ float Ur[16][16];      // Re U[b][col]
    __shared__ float Ui[16][16];      // Im U[b][col]
    __shared__ float ReE[4][16][16];  // Re(U^dag Z_w U)
    int t = threadIdx.x;

    // Stage 1: 16 gate matrices (parallel trig)
    if (t < 16) {
        float phi = qw[t * 3 + 0], theta = qw[t * 3 + 1], omega = qw[t * 3 + 2];
        float ct = cosf(0.5f * theta), st = sinf(0.5f * theta);
        float ha = 0.5f * (phi + omega), hd = 0.5f * (phi - omega);
        float emr = cosf(ha), emi = -sinf(ha);
        float edr = cosf(hd), edi =  sinf(hd);
        g[t][0] =  emr * ct; g[t][1] =  emi * ct;   // u00
        g[t][2] = -edr * st; g[t][3] = -edi * st;   // u01
        g[t][4] =  edr * st; g[t][5] = -edi * st;   // u10
        g[t][6] =  emr * ct; g[t][7] = -emi * ct;   // u11
    }
    __syncthreads();

    // Stage 2: thread t (<16) evolves basis column e_t through the circuit
    if (t < 16) {
        float ar[16], ai[16];
#pragma unroll
        for (int b = 0; b < 16; ++b) { ar[b] = (b == t) ? 1.f : 0.f; ai[b] = 0.f; }
#pragma unroll
        for (int l = 0; l < 4; ++l) {
#pragma unroll
            for (int w = 0; w < 4; ++w) {
                int gi = l * 4 + w;
                float u00r = g[gi][0], u00i = g[gi][1], u01r = g[gi][2], u01i = g[gi][3];
                float u10r = g[gi][4], u10i = g[gi][5], u11r = g[gi][6], u11i = g[gi][7];
                int mask = 8 >> w;   // wire w <-> bit (3-w)
#pragma unroll
                for (int b = 0; b < 16; ++b) {
                    if (b & mask) continue;
                    int b1 = b | mask;
                    float xr = ar[b], xi = ai[b], yr = ar[b1], yi = ai[b1];
                    ar[b]  = u00r * xr - u00i * xi + u01r * yr - u01i * yi;
                    ai[b]  = u00r * xi + u00i * xr + u01r * yi + u01i * yr;
                    ar[b1] = u10r * xr - u10i * xi + u11r * yr - u11i * yi;
                    ai[b1] = u10r * xi + u10i * xr + u11r * yi + u11i * yr;
                }
            }
#pragma unroll
            for (int w = 0; w < 4; ++w) {   // CNOT ring
                int cm = 8 >> w, tm = 8 >> ((w + 1) & 3);
#pragma unroll
                for (int b = 0; b < 16; ++b) {
                    if ((b & cm) && !(b & tm)) {
                        int b1 = b | tm;
                        float tr = ar[b], ti = ai[b];
                        ar[b] = ar[b1]; ai[b] = ai[b1];
                        ar[b1] = tr;    ai[b1] = ti;
                    }
                }
            }
        }
#pragma unroll
        for (int b = 0; b < 16; ++b) { Ur[b][t] = ar[b]; Ui[b][t] = ai[b]; }
    }
    __syncthreads();

    // Stage 3: ReE_w[i][j] = sum_b z_w(b) * (Ur[b][i]Ur[b][j] + Ui[b][i]Ui[b][j])
    for (int idx = t; idx < 1024; idx += 256) {
        int w = idx >> 8, i = (idx >> 4) & 15, j = idx & 15;
        float acc = 0.f;
#pragma unroll
        for (int b = 0; b < 16; ++b) {
            float z = ((b >> (3 - w)) & 1) ? -1.f : 1.f;
            acc += z * (Ur[b][i] * Ur[b][j] + Ui[b][i] * Ui[b][j]);
        }
        ReE[w][i][j] = acc;
    }
    __syncthreads();

    // Stage 4: C[(t01*9+t23)*4 + w] = (1/16) sum_i sign_t(i) ReE_w[i][i^xmask]
    for (int idx = t; idx < 324; idx += 256) {
        int w = idx & 3, tt = idx >> 2;        // tt = t01*9 + t23, 0..80
        int t01 = tt / 9, t23 = tt % 9;
        int tq[4] = { t01 / 3, t01 % 3, t23 / 3, t23 % 3 };  // 0=I,1=X,2=Z
        int xmask = 0, zmask = 0;
#pragma unroll
        for (int k = 0; k < 4; ++k) {
            if (tq[k] == 1) xmask |= 8 >> k;
            if (tq[k] == 2) zmask |= 8 >> k;
        }
        float acc = 0.f;
#pragma unroll
        for (int i = 0; i < 16; ++i) {
            float sgn = (__popc(i & zmask) & 1) ? -1.f : 1.f;
            acc += sgn * ReE[w][i][i ^ xmask];
        }
        Cg[idx] = acc * 0.0625f;
    }
}

__global__ __launch_bounds__(256) void qlayer_main(
        const float4* __restrict__ x, const float* __restrict__ Cg,
        float4* __restrict__ out, int B) {
    __shared__ __align__(16) float C[324];
    for (int k = threadIdx.x; k < 324; k += 256) C[k] = Cg[k];
    __syncthreads();

    int i = blockIdx.x * 256 + threadIdx.x;
    if (i >= B) return;
    float4 xv = x[i];
    float s0, c0, s1, c1, s2, c2, s3, c3;
    __sincosf(xv.x, &s0, &c0);
    __sincosf(xv.y, &s1, &c1);
    __sincosf(xv.z, &s2, &c2);
    __sincosf(xv.w, &s3, &c3);
    float m0[3] = {1.f, s0, c0}, m1[3] = {1.f, s1, c1};
    float m2[3] = {1.f, s2, c2}, m3[3] = {1.f, s3, c3};
    float M01[9], M23[9];
#pragma unroll
    for (int a = 0; a < 3; ++a)
#pragma unroll
        for (int b = 0; b < 3; ++b) {
            M01[a * 3 + b] = m0[a] * m1[b];
            M23[a * 3 + b] = m2[a] * m3[b];
        }

    float e0 = 0.f, e1 = 0.f, e2 = 0.f, e3 = 0.f;
#pragma unroll
    for (int t01 = 0; t01 < 9; ++t01) {
        float h0 = 0.f, h1 = 0.f, h2 = 0.f, h3 = 0.f;
#pragma unroll
        for (int t23 = 0; t23 < 9; ++t23) {
            const float4 c4 = *(const float4*)&C[(t01 * 9 + t23) * 4];
            float mv = M23[t23];
            h0 = fmaf(c4.x, mv, h0);
            h1 = fmaf(c4.y, mv, h1);
            h2 = fmaf(c4.z, mv, h2);
            h3 = fmaf(c4.w, mv, h3);
        }
        float mu = M01[t01];
        e0 = fmaf(mu, h0, e0);
        e1 = fmaf(mu, h1, e1);
        e2 = fmaf(mu, h2, e2);
        e3 = fmaf(mu, h3, e3);
    }
    out[i] = make_float4(e0, e1, e2, e3);
}

extern "C" void kernel_launch(void* const* d_in, const int* in_sizes, int n_in,
                              void* d_out, int out_size, void* d_ws, size_t ws_size,
                              hipStream_t stream) {
    const float4* x  = (const float4*)d_in[0];   // (B,4) float32
    const float*  qw = (const float*)d_in[1];    // (4,4,3) float32
    float* Cg = (float*)d_ws;                    // 324 floats
    float4* out = (float4*)d_out;                // (B,4) float32
    int B = in_sizes[0] / 4;

    hipLaunchKernelGGL(build_C, dim3(1), dim3(256), 0, stream, qw, Cg);

    int blocks = (B + 255) / 256;
    hipLaunchKernelGGL(qlayer_main, dim3(blocks), dim3(256), 0, stream,
                       x, Cg, out, B);
}

// Round 4
// 81.100 us; speedup vs baseline: 1.7101x; 1.0425x over previous
//
#include <hip/hip_runtime.h>
#include <math.h>

// ---------------------------------------------------------------------------
// 4-qubit statevector layer, fully collapsed:
//   e_w = sum_{t in {I,X,Z}^4} C_w[t] * prod_k m_k[t_k],  m_k = [1, sin x, cos x]
// C (4 x 81 floats) depends only on q_weights: built once per call by build_C.
// build_C v2: NO per-thread arrays (v1 spilled to scratch -> 46 us on one
// wave). State lives in LDS, 256 threads = 16 amplitudes x 16 columns, one
// barrier per gate step via ping-pong buffers. CNOT ring = one permutation.
// ---------------------------------------------------------------------------

__global__ __launch_bounds__(256) void build_C(const float* __restrict__ qw,
                                               float* __restrict__ Cg) {
    __shared__ float g[16][8];          // per-gate 2x2 complex entries
    __shared__ float Ar[2][16][16];     // ping-pong Re state, [buf][amp b][col]
    __shared__ float Ai[2][16][16];
    __shared__ float ReE[4][16][16];    // Re(U^dag Z_w U)
    int t = threadIdx.x;
    int b   = t >> 4;    // amplitude index this thread owns
    int col = t & 15;    // basis column

    // Stage 1: 16 gate matrices, parallel fast trig
    if (t < 16) {
        float phi = qw[t * 3 + 0], theta = qw[t * 3 + 1], omega = qw[t * 3 + 2];
        float st, ct, sha, cha, shd, chd;
        __sincosf(0.5f * theta, &st, &ct);
        __sincosf(0.5f * (phi + omega), &sha, &cha);   // em = cha - i*sha
        __sincosf(0.5f * (phi - omega), &shd, &chd);   // ed = chd + i*shd
        g[t][0] =  cha * ct; g[t][1] = -sha * ct;   // u00
        g[t][2] = -chd * st; g[t][3] = -shd * st;   // u01
        g[t][4] =  chd * st; g[t][5] = -shd * st;   // u10
        g[t][6] =  cha * ct; g[t][7] =  sha * ct;   // u11
    }
    // init state = identity columns
    Ar[0][b][col] = (b == col) ? 1.f : 0.f;
    Ai[0][b][col] = 0.f;
    __syncthreads();

    // Precompute CNOT-ring permutation: new[b] = old[perm(b)]
    // gates applied in order w=0,1,2,3 => compose sigma's in reverse order.
    int perm = b;
#pragma unroll
    for (int w = 3; w >= 0; --w) {
        int cm = 8 >> w, tm = 8 >> ((w + 1) & 3);
        perm = (perm & cm) ? (perm ^ tm) : perm;
    }

    int p = 0;
    for (int l = 0; l < 4; ++l) {
#pragma unroll
        for (int w = 0; w < 4; ++w) {
            int gi = l * 4 + w;
            int m = 8 >> w;              // wire w <-> bit (3-w)
            int lo = b & ~m, hi = b | m;
            bool isHi = (b & m) != 0;
            float cAr = isHi ? g[gi][4] : g[gi][0];
            float cAi = isHi ? g[gi][5] : g[gi][1];
            float cBr = isHi ? g[gi][6] : g[gi][2];
            float cBi = isHi ? g[gi][7] : g[gi][3];
            float alor = Ar[p][lo][col], aloi = Ai[p][lo][col];
            float ahir = Ar[p][hi][col], ahii = Ai[p][hi][col];
            float nr = cAr * alor - cAi * aloi + cBr * ahir - cBi * ahii;
            float ni = cAr * aloi + cAi * alor + cBr * ahii + cBi * ahir;
            Ar[1 - p][b][col] = nr;
            Ai[1 - p][b][col] = ni;
            p = 1 - p;
            __syncthreads();
        }
        // CNOT ring as one permutation step
        float nr = Ar[p][perm][col], ni = Ai[p][perm][col];
        Ar[1 - p][b][col] = nr;
        Ai[1 - p][b][col] = ni;
        p = 1 - p;
        __syncthreads();
    }

    // Stage 3: ReE_w[i][j] = sum_b z_w(b) * (Ur[b][i]Ur[b][j] + Ui[b][i]Ui[b][j])
    for (int idx = t; idx < 1024; idx += 256) {
        int w = idx >> 8, i = (idx >> 4) & 15, j = idx & 15;
        float acc = 0.f;
#pragma unroll
        for (int bb = 0; bb < 16; ++bb) {
            float z = ((bb >> (3 - w)) & 1) ? -1.f : 1.f;
            acc += z * (Ar[p][bb][i] * Ar[p][bb][j] + Ai[p][bb][i] * Ai[p][bb][j]);
        }
        ReE[w][i][j] = acc;
    }
    __syncthreads();

    // Stage 4: C[(t01*9+t23)*4 + w] = (1/16) sum_i sign_t(i) ReE_w[i][i^xmask]
    for (int idx = t; idx < 324; idx += 256) {
        int w = idx & 3, tt = idx >> 2;        // tt = t01*9 + t23, 0..80
        int t01 = tt / 9, t23 = tt % 9;
        int d0 = t01 / 3, d1 = t01 % 3, d2 = t23 / 3, d3 = t23 % 3;  // 0=I,1=X,2=Z
        int xmask = ((d0 == 1) << 3) | ((d1 == 1) << 2) | ((d2 == 1) << 1) | (d3 == 1);
        int zmask = ((d0 == 2) << 3) | ((d1 == 2) << 2) | ((d2 == 2) << 1) | (d3 == 2);
        float acc = 0.f;
#pragma unroll
        for (int i = 0; i < 16; ++i) {
            float sgn = (__popc(i & zmask) & 1) ? -1.f : 1.f;
            acc += sgn * ReE[w][i][i ^ xmask];
        }
        Cg[idx] = acc * 0.0625f;
    }
}

__global__ __launch_bounds__(256) void qlayer_main(
        const float4* __restrict__ x, const float* __restrict__ Cg,
        float4* __restrict__ out, int B) {
    __shared__ __align__(16) float C[324];
    for (int k = threadIdx.x; k < 324; k += 256) C[k] = Cg[k];
    __syncthreads();

    int half = B >> 1;
    int i = blockIdx.x * 256 + threadIdx.x;
    if (i >= half) {
        // odd-B tail (not hit for B=1M, kept for safety)
        if (i == half && (B & 1)) {
            float4 xv = x[B - 1];
            float s0, c0, s1, c1, s2, c2, s3, c3;
            __sincosf(xv.x, &s0, &c0); __sincosf(xv.y, &s1, &c1);
            __sincosf(xv.z, &s2, &c2); __sincosf(xv.w, &s3, &c3);
            float m0[3] = {1.f, s0, c0}, m1[3] = {1.f, s1, c1};
            float m2[3] = {1.f, s2, c2}, m3[3] = {1.f, s3, c3};
            float e0 = 0.f, e1 = 0.f, e2 = 0.f, e3 = 0.f;
            for (int t01 = 0; t01 < 9; ++t01)
                for (int t23 = 0; t23 < 9; ++t23) {
                    float mv = m0[t01 / 3] * m1[t01 % 3] * m2[t23 / 3] * m3[t23 % 3];
                    const float4 c4 = *(const float4*)&C[(t01 * 9 + t23) * 4];
                    e0 = fmaf(c4.x, mv, e0); e1 = fmaf(c4.y, mv, e1);
                    e2 = fmaf(c4.z, mv, e2); e3 = fmaf(c4.w, mv, e3);
                }
            out[B - 1] = make_float4(e0, e1, e2, e3);
        }
        return;
    }

    float4 xa = x[i];
    float4 xb = x[i + half];
    float as0, ac0, as1, ac1, as2, ac2, as3, ac3;
    float bs0, bc0, bs1, bc1, bs2, bc2, bs3, bc3;
    __sincosf(xa.x, &as0, &ac0); __sincosf(xa.y, &as1, &ac1);
    __sincosf(xa.z, &as2, &ac2); __sincosf(xa.w, &as3, &ac3);
    __sincosf(xb.x, &bs0, &bc0); __sincosf(xb.y, &bs1, &bc1);
    __sincosf(xb.z, &bs2, &bc2); __sincosf(xb.w, &bs3, &bc3);

    float am0[3] = {1.f, as0, ac0}, am1[3] = {1.f, as1, ac1};
    float am2[3] = {1.f, as2, ac2}, am3[3] = {1.f, as3, ac3};
    float bm0[3] = {1.f, bs0, bc0}, bm1[3] = {1.f, bs1, bc1};
    float bm2[3] = {1.f, bs2, bc2}, bm3[3] = {1.f, bs3, bc3};
    float aM01[9], aM23[9], bM01[9], bM23[9];
#pragma unroll
    for (int a = 0; a < 3; ++a)
#pragma unroll
        for (int c = 0; c < 3; ++c) {
            aM01[a * 3 + c] = am0[a] * am1[c];
            aM23[a * 3 + c] = am2[a] * am3[c];
            bM01[a * 3 + c] = bm0[a] * bm1[c];
            bM23[a * 3 + c] = bm2[a] * bm3[c];
        }

    float ae0 = 0.f, ae1 = 0.f, ae2 = 0.f, ae3 = 0.f;
    float be0 = 0.f, be1 = 0.f, be2 = 0.f, be3 = 0.f;
#pragma unroll
    for (int t01 = 0; t01 < 9; ++t01) {
        float ah0 = 0.f, ah1 = 0.f, ah2 = 0.f, ah3 = 0.f;
        float bh0 = 0.f, bh1 = 0.f, bh2 = 0.f, bh3 = 0.f;
#pragma unroll
        for (int t23 = 0; t23 < 9; ++t23) {
            const float4 c4 = *(const float4*)&C[(t01 * 9 + t23) * 4];
            float av = aM23[t23], bv = bM23[t23];
            ah0 = fmaf(c4.x, av, ah0); bh0 = fmaf(c4.x, bv, bh0);
            ah1 = fmaf(c4.y, av, ah1); bh1 = fmaf(c4.y, bv, bh1);
            ah2 = fmaf(c4.z, av, ah2); bh2 = fmaf(c4.z, bv, bh2);
            ah3 = fmaf(c4.w, av, ah3); bh3 = fmaf(c4.w, bv, bh3);
        }
        float au = aM01[t01], bu = bM01[t01];
        ae0 = fmaf(au, ah0, ae0); be0 = fmaf(bu, bh0, be0);
        ae1 = fmaf(au, ah1, ae1); be1 = fmaf(bu, bh1, be1);
        ae2 = fmaf(au, ah2, ae2); be2 = fmaf(bu, bh2, be2);
        ae3 = fmaf(au, ah3, ae3); be3 = fmaf(bu, bh3, be3);
    }
    out[i]        = make_float4(ae0, ae1, ae2, ae3);
    out[i + half] = make_float4(be0, be1, be2, be3);
}

extern "C" void kernel_launch(void* const* d_in, const int* in_sizes, int n_in,
                              void* d_out, int out_size, void* d_ws, size_t ws_size,
                              hipStream_t stream) {
    const float4* x  = (const float4*)d_in[0];   // (B,4) float32
    const float*  qw = (const float*)d_in[1];    // (4,4,3) float32
    float* Cg = (float*)d_ws;                    // 324 floats
    float4* out = (float4*)d_out;                // (B,4) float32
    int B = in_sizes[0] / 4;

    hipLaunchKernelGGL(build_C, dim3(1), dim3(256), 0, stream, qw, Cg);

    int half = B >> 1;
    int blocks = (half + 255) / 256;
    if (blocks < 1) blocks = 1;
    hipLaunchKernelGGL(qlayer_main, dim3(blocks), dim3(256), 0, stream,
                       x, Cg, out, B);
}